// Round 2
// baseline (541.438 us; speedup 1.0000x reference)
//
#include <hip/hip_runtime.h>
#include <hip/hip_bf16.h>

// PixelContrastLossOnlyNeg on MI355X.
// feats [16,256,128,128] f32, queue [256,256] f32, labels [262144,256] i32 -> scalar f32.
// Fused bf16-MFMA GEMM (N=262144, M=256, K=256) + masked-exp reduction.
// Memory floor: feats 256MB + labels 256MB = 512MB -> ~81us @ 6.3TB/s.
//
// v2 vs v1: reg-staged bf16 B-fragments (pack once, not once per wave),
// LDS 68.6KB -> 34KB => 4 blocks/CU, contiguous ds_read_b128/ds_write_b128
// (zero bank conflicts), exp2-domain logits (one transcendental per term).
// v2b: plain exp2f instead of guarded __builtin_amdgcn_exp2f (same v_exp_f32).

typedef __bf16 bf16x8 __attribute__((ext_vector_type(8)));
typedef float floatx4 __attribute__((ext_vector_type(4)));

union BFrag {
  unsigned int u32[4];
  uint4 v;
  bf16x8 bf;
};

// Pack two f32 -> two bf16 (round-half-up; bias ~2^-17 rel, irrelevant here). 5 VALU ops.
__device__ __forceinline__ unsigned int pack_bf2(float a, float b) {
  unsigned int ua = __float_as_uint(a) + 0x8000u;
  unsigned int ub = __float_as_uint(b) + 0x8000u;
  return (ua >> 16) | (ub & 0xffff0000u);
}

// ---------------------------------------------------------------------------
// k0: queue f32 -> bf16 * (log2e/T), stored pre-swizzled in A-fragment lane
// order: tile t = m16*8 + ks, lane L holds A[m=m16*16+(L&15)][k=ks*32+(L>>4)*8+j],
// j=0..7 -> 16B at (t*64+L)*16. Main-kernel A-frag load is one coalesced
// dwordx4 per (tile,lane). Also zeroes the global accumulators.
// Folding log2(e) means the MFMA output is already in exp2 domain:
// exp(logit/T) == exp2(acc).
// ---------------------------------------------------------------------------
__global__ void qprep(const float* __restrict__ queue,
                      unsigned short* __restrict__ qs,
                      float* __restrict__ accum) {
  const int gt = blockIdx.x * 256 + threadIdx.x;  // 0..8191
  const int t = gt >> 6;
  const int lane = gt & 63;
  const int m = ((t >> 3) << 4) | (lane & 15);
  const int k0 = ((t & 7) << 5) | ((lane >> 4) << 3);
  const float* qr = queue + m * 256 + k0;
  const float SCALE = 20.6099291556f;  // (1/0.07) * log2(e) folded into Q
  BFrag u;
#pragma unroll
  for (int j = 0; j < 4; ++j)
    u.u32[j] = pack_bf2(qr[2 * j] * SCALE, qr[2 * j + 1] * SCALE);
  *(uint4*)(qs + (size_t)gt * 8) = u.v;
  if (gt == 0) { accum[0] = 0.0f; accum[1] = 0.0f; }
}

// ---------------------------------------------------------------------------
// k1: main fused kernel. Block = 64 pixels x 256 classes, 256 threads (4 waves),
// wave w owns M rows [64w, 64w+64). Grid = 16 batches * 256 tiles = 4096 blocks.
//
// Staging: thread (w, lane=(qd,s)) owns 8 B-fragments: for O in {2w,2w+1},
// N in 0..3, octet o = O*4+qd (k = 8o..8o+7), pixel n = N*16+s. 8 scalar
// dword loads (wave-level: 4 x 64B segments per instr), 4 pack_bf2, one
// ds_write_b128 at Bf[(O*4+N)*64 + lane] -> contiguous, conflict-free.
// K-loop B read: tile T = ks*4+nt at Bf[T*64+lane] -> contiguous b128.
// ---------------------------------------------------------------------------
__global__ __launch_bounds__(256, 4) void pcl_main(
    const float* __restrict__ feats,
    const int* __restrict__ labels,
    const unsigned short* __restrict__ qs,
    float* __restrict__ accum) {
  __shared__ uint4 Bf[2048];         // 32 KB: bf16 B-fragments, tile T = ks*4+nt
  __shared__ float Red[8][64];       // per-wave neg/pos partials (2 KB)

  const int bx = blockIdx.x;
  const int bidx = bx >> 8;          // batch
  const int hw0 = (bx & 255) << 6;   // pixel tile base within batch
  const int tid = threadIdx.x;
  const int w = tid >> 6;
  const int lane = tid & 63;
  const int qd = lane >> 4;          // quad 0..3
  const int s = lane & 15;

  // ---- stage F tile: f32 -> bf16 fragments, packed ONCE for the block ----
  {
    const float* gbase = feats + (size_t)bidx * (256 * 16384) + hw0;
#pragma unroll
    for (int O2 = 0; O2 < 2; ++O2) {
      const int O = (w << 1) + O2;              // 0..7
      const int o = (O << 2) + qd;              // k-octet 0..31, k0 = 8o
#pragma unroll
      for (int N = 0; N < 4; ++N) {
        const float* gp = gbase + (size_t)(o << 3) * 16384 + (N << 4) + s;
        float v0 = gp[0];
        float v1 = gp[16384];
        float v2 = gp[2 * 16384];
        float v3 = gp[3 * 16384];
        float v4 = gp[4 * 16384];
        float v5 = gp[5 * 16384];
        float v6 = gp[6 * 16384];
        float v7 = gp[7 * 16384];
        BFrag u;
        u.u32[0] = pack_bf2(v0, v1);
        u.u32[1] = pack_bf2(v2, v3);
        u.u32[2] = pack_bf2(v4, v5);
        u.u32[3] = pack_bf2(v6, v7);
        Bf[((O << 2) + N) * 64 + lane] = u.v;   // contiguous b128 write
      }
    }
  }

  floatx4 acc[4][4];
#pragma unroll
  for (int mt = 0; mt < 4; ++mt)
#pragma unroll
    for (int nt = 0; nt < 4; ++nt)
      acc[mt][nt] = floatx4{0.0f, 0.0f, 0.0f, 0.0f};

  __syncthreads();

  // ---- K loop: 8 steps of 32, 16 MFMAs each ----
  const bf16x8* qfrag = (const bf16x8*)qs;
  const bf16x8* bfrag = (const bf16x8*)Bf;
#pragma unroll
  for (int ks = 0; ks < 8; ++ks) {
    bf16x8 af[4];
#pragma unroll
    for (int mt = 0; mt < 4; ++mt) {
      const int t = ((((w << 2) + mt) << 3) | ks);
      af[mt] = qfrag[t * 64 + lane];            // coalesced 1KB, L2-hot
    }
    bf16x8 bfv[4];
#pragma unroll
    for (int nt = 0; nt < 4; ++nt)
      bfv[nt] = bfrag[((ks << 2) + nt) * 64 + lane];  // contiguous b128 read
#pragma unroll
    for (int mt = 0; mt < 4; ++mt)
#pragma unroll
      for (int nt = 0; nt < 4; ++nt)
        acc[mt][nt] = __builtin_amdgcn_mfma_f32_16x16x32_bf16(af[mt], bfv[nt],
                                                              acc[mt][nt], 0, 0, 0);
  }

  // ---- epilogue: lane holds C[m = 64w+16mt+4qd+r][n = 16nt+s] ----
  // acc is in exp2 domain (log2e folded into Q). One transcendental per term:
  // y=0 -> nn += exp2(acc); y=1 -> pp += exp2(-acc). Sign flip via XOR.
  const size_t nbase = (size_t)bx << 6;  // global pixel base

  float nn[4] = {0.f, 0.f, 0.f, 0.f};  // sum_neg partials per nt
  float pp[4] = {0.f, 0.f, 0.f, 0.f};  // sum_pos partials per nt
#define ACCUM_TERM(LV, AV)                                                \
  do {                                                                    \
    const unsigned int y_ = (unsigned int)(LV);                           \
    const float x_ = __uint_as_float(__float_as_uint(AV) ^ (y_ << 31));   \
    const float e_ = exp2f(x_);                                           \
    nn[nt] += y_ ? 0.0f : e_;                                             \
    pp[nt] += y_ ? e_ : 0.0f;                                             \
  } while (0)

#pragma unroll
  for (int mt = 0; mt < 4; ++mt) {
    int4 lab[4];
#pragma unroll
    for (int nt = 0; nt < 4; ++nt)
      lab[nt] = *(const int4*)(labels + ((nbase + (nt << 4) + s) << 8) +
                               (w << 6) + (mt << 4) + (qd << 2));
#pragma unroll
    for (int nt = 0; nt < 4; ++nt) {
      const int4 lb = lab[nt];
      const floatx4 a = acc[mt][nt];
      ACCUM_TERM(lb.x, a[0]);
      ACCUM_TERM(lb.y, a[1]);
      ACCUM_TERM(lb.z, a[2]);
      ACCUM_TERM(lb.w, a[3]);
    }
  }
#undef ACCUM_TERM

  // quad-reduce (lanes l, l+16, l+32, l+48 share a pixel)
#pragma unroll
  for (int nt = 0; nt < 4; ++nt) {
    nn[nt] += __shfl_xor(nn[nt], 16);
    nn[nt] += __shfl_xor(nn[nt], 32);
    pp[nt] += __shfl_xor(pp[nt], 16);
    pp[nt] += __shfl_xor(pp[nt], 32);
  }
  if (lane < 16) {
#pragma unroll
    for (int nt = 0; nt < 4; ++nt) {
      Red[(w << 1) | 0][(nt << 4) + lane] = nn[nt];
      Red[(w << 1) | 1][(nt << 4) + lane] = pp[nt];
    }
  }
  __syncthreads();

  if (tid < 64) {
    const float sn = Red[0][tid] + Red[2][tid] + Red[4][tid] + Red[6][tid];
    const float sp = Red[1][tid] + Red[3][tid] + Red[5][tid] + Red[7][tid];
    float loss = logf(sn * sp + 1.0f);
    float c = (loss != 0.0f) ? 1.0f : 0.0f;
#pragma unroll
    for (int off = 32; off > 0; off >>= 1) {
      loss += __shfl_xor(loss, off);
      c += __shfl_xor(c, off);
    }
    if (tid == 0) {
      atomicAdd(&accum[0], loss);
      atomicAdd(&accum[1], c);
    }
  }
}

// ---------------------------------------------------------------------------
// k2: scalar finalize. Mirrors where(lb_num==0, 0, sum/max(lb_num,1)).
// ---------------------------------------------------------------------------
__global__ void pcl_finalize(const float* __restrict__ accum,
                             float* __restrict__ out) {
  const float ssum = accum[0];
  const float c = accum[1];
  out[0] = (c != 0.0f) ? (ssum / c) : 0.0f;
}

extern "C" void kernel_launch(void* const* d_in, const int* in_sizes, int n_in,
                              void* d_out, int out_size, void* d_ws, size_t ws_size,
                              hipStream_t stream) {
  (void)in_sizes; (void)n_in; (void)out_size; (void)ws_size;
  const float* feats = (const float*)d_in[0];
  const float* queue = (const float*)d_in[1];
  const int* labels = (const int*)d_in[2];

  // workspace: [0,128KB) swizzled bf16 queue, [128KB, 128KB+8B) accumulators
  unsigned short* qs = (unsigned short*)d_ws;
  float* accum = (float*)((char*)d_ws + 256 * 256 * sizeof(unsigned short));

  qprep<<<32, 256, 0, stream>>>(queue, qs, accum);
  pcl_main<<<4096, 256, 0, stream>>>(feats, labels, qs, accum);
  pcl_finalize<<<1, 1, 0, stream>>>(accum, (float*)d_out);
}